// Round 1
// baseline (8930.373 us; speedup 1.0000x reference)
//
#include <hip/hip_runtime.h>
#include <hip/hip_bf16.h>

#define MAX_N 4096
#define MAX_S 20000
#define NTHREADS 1024

// ---------------------------------------------------------------------------
// Kernel A: compute greedy processing order = argsort(-precondWL), stable.
// rank[i] = #{j : w[j] > w[i]} + #{j < i : w[j] == w[i]}  (strict total order
// => ranks are a permutation).  order[rank] = i.
// ---------------------------------------------------------------------------
__global__ void LegalizeDSPRAM_rank_kernel(const float* __restrict__ w,
                                           int* __restrict__ order, int N) {
    __shared__ float sw[MAX_N];
    int tid = threadIdx.x;
    for (int j = tid; j < N; j += blockDim.x) sw[j] = w[j];
    __syncthreads();
    int i = blockIdx.x * blockDim.x + tid;
    if (i < N) {
        float wi = sw[i];
        int rank = 0;
        for (int j = 0; j < N; ++j) {
            float wj = sw[j];
            rank += (wj > wi) || (wj == wi && j < i);
        }
        order[rank] = i;
    }
}

// ---------------------------------------------------------------------------
// Kernel B: single-block sequential greedy assignment.
// Sites live in LDS as float2 (160000 B).  A taken site has its x set to +inf
// so its distance becomes +inf (N < S guarantees a finite winner each step).
// Per step: strided scan with packed (dist_bits<<32 | site_idx) u64 so that
// u64-min == lexicographic (min dist, then min index) == jnp.argmin semantics.
// Distances computed exactly as the reference: fabsf(lx-sx)+fabsf(ly-sy), f32.
// ---------------------------------------------------------------------------
__global__ __launch_bounds__(NTHREADS, 1)
void LegalizeDSPRAM_greedy_kernel(const float* __restrict__ locX,
                                  const float* __restrict__ locY,
                                  const float* __restrict__ sites,
                                  const int* __restrict__ order,
                                  float* __restrict__ out,
                                  int N, int S) {
    __shared__ float2 s_sites[MAX_S];
    __shared__ unsigned long long sBest;

    int tid = threadIdx.x;
    for (int j = tid; j < S; j += NTHREADS) {
        s_sites[j] = make_float2(sites[2 * j], sites[2 * j + 1]);
    }
    if (tid == 0) sBest = ~0ull;
    __syncthreads();

    float  maxMove = 0.0f;
    double sumMove = 0.0;

    for (int t = 0; t < N; ++t) {
        int   i  = order[t];
        float lx = locX[i];
        float ly = locY[i];

        unsigned long long best = ~0ull;
        for (int j = tid; j < S; j += NTHREADS) {
            float2 s = s_sites[j];
            float  d = fabsf(lx - s.x) + fabsf(ly - s.y);
            unsigned long long p =
                ((unsigned long long)__float_as_uint(d) << 32) |
                (unsigned long long)(unsigned)j;
            best = (p < best) ? p : best;   // per-thread j ascending => keeps first index on ties
        }

        // wave-level lexicographic min (64 lanes)
        #pragma unroll
        for (int m = 32; m >= 1; m >>= 1) {
            unsigned long long o = __shfl_xor(best, m);
            best = (o < best) ? o : best;
        }
        if ((tid & 63) == 0) atomicMin(&sBest, best);
        __syncthreads();

        if (tid == 0) {
            unsigned long long wwin = sBest;
            int   j  = (int)(unsigned)(wwin & 0xffffffffull);
            float sx = s_sites[j].x;   // winner is untaken => original coords
            float sy = s_sites[j].y;
            out[i]     = sx;
            out[N + i] = sy;
            float mv = fabsf(lx - sx) + fabsf(ly - sy);
            maxMove  = fmaxf(maxMove, mv);
            sumMove += (double)mv;
            s_sites[j].x = __int_as_float(0x7f800000);  // +inf => taken
            sBest = ~0ull;
        }
        __syncthreads();
    }

    if (tid == 0) {
        out[2 * N]     = maxMove;
        out[2 * N + 1] = (float)(sumMove / (double)N);
    }
}

extern "C" void kernel_launch(void* const* d_in, const int* in_sizes, int n_in,
                              void* d_out, int out_size, void* d_ws, size_t ws_size,
                              hipStream_t stream) {
    const float* locX      = (const float*)d_in[0];
    const float* locY      = (const float*)d_in[1];
    const float* precondWL = (const float*)d_in[2];
    const float* sites     = (const float*)d_in[3];
    float* out = (float*)d_out;

    int N = in_sizes[0];
    int S = in_sizes[3] / 2;

    int* order = (int*)d_ws;

    int blocks = (N + 255) / 256;
    LegalizeDSPRAM_rank_kernel<<<blocks, 256, 0, stream>>>(precondWL, order, N);
    LegalizeDSPRAM_greedy_kernel<<<1, NTHREADS, 0, stream>>>(
        locX, locY, sites, order, out, N, S);
}

// Round 3
// 1382.285 us; speedup vs baseline: 6.4606x; 6.4606x over previous
//
#include <hip/hip_runtime.h>
#include <hip/hip_bf16.h>

typedef unsigned long long u64;
typedef unsigned int u32;

#define KCAND 16
#define PAD_ENTRIES 192   // 12 pad rank-slots * 16 entries

// ---------------------------------------------------------------------------
// K1: order = stable argsort(-w).  One wave per instance: rank via counting.
// Also initializes the candidate-array padding (sentinels) used by K3 prefetch.
// ---------------------------------------------------------------------------
__global__ void k_rank(const float* __restrict__ w, int* __restrict__ order,
                       u64* __restrict__ cand, int N) {
    int gid  = blockIdx.x * blockDim.x + threadIdx.x;
    int wave = gid >> 6, lane = gid & 63;
    if (gid < PAD_ENTRIES) cand[(size_t)N * KCAND + gid] = ~0ull;
    if (wave >= N) return;
    float wi = w[wave];
    int cnt = 0;
    for (int j = lane; j < N; j += 64) {
        float wj = w[j];
        cnt += (wj > wi) || (wj == wi && j < wave);
    }
    #pragma unroll
    for (int m = 32; m >= 1; m >>= 1) cnt += __shfl_xor(cnt, m);
    if (lane == 0) order[cnt] = wave;
}

// ---------------------------------------------------------------------------
// K2: per-RANK exact top-16 candidate list (sorted ascending by packed key
// (dist_bits<<32)|j), truncated by the coverage bound.  One wave per rank
// slot t; the instance is order[t] (k_rank ran earlier on the same stream).
// Each lane keeps its sorted top-4 over its strided 1/64 of the sites;
// coverage = min over lanes of lane's 4th-smallest (all sites with key <
// coverage are guaranteed present among the 256 lane-candidates); 16
// extraction rounds of wave-wide u64-min produce the global top-16.
// Entries with key >= coverage are stored as sentinel ~0ull.
// ---------------------------------------------------------------------------
__global__ void k_cand(const float* __restrict__ locX,
                       const float* __restrict__ locY,
                       const float* __restrict__ sites,
                       const int* __restrict__ order,
                       u64* __restrict__ cand, int N, int S) {
    int gid  = blockIdx.x * blockDim.x + threadIdx.x;
    int wave = gid >> 6, lane = gid & 63;   // wave == rank slot t
    if (wave >= N) return;
    int inst = order[wave];
    float lx = locX[inst], ly = locY[inst];
    const float2* s2 = (const float2*)sites;

    u64 c0 = ~0ull, c1 = ~0ull, c2 = ~0ull, c3 = ~0ull;
    for (int j = lane; j < S; j += 64) {
        float2 s = s2[j];
        float  d = fabsf(lx - s.x) + fabsf(ly - s.y);
        u64 k = ((u64)__float_as_uint(d) << 32) | (u32)j;
        if (k < c3) {  // sorted insert of k into (c0<=c1<=c2<=c3), drop max
            u64 n3 = (k < c2) ? c2 : k;
            u64 n2 = (k < c2) ? ((k < c1) ? c1 : k) : c2;
            u64 n1 = (k < c1) ? ((k < c0) ? c0 : k) : c1;
            u64 n0 = (k < c0) ? k : c0;
            c0 = n0; c1 = n1; c2 = n2; c3 = n3;
        }
    }
    // coverage bound (before extraction destroys the lists)
    u64 cov = c3;
    #pragma unroll
    for (int m = 32; m >= 1; m >>= 1) {
        u64 o = __shfl_xor(cov, m);
        cov = (o < cov) ? o : cov;
    }
    // 16 extraction rounds: global min; unique winner shifts its list down
    for (int r = 0; r < KCAND; ++r) {
        u64 h = c0;
        #pragma unroll
        for (int m = 32; m >= 1; m >>= 1) {
            u64 o = __shfl_xor(h, m);
            h = (o < h) ? o : h;
        }
        if (c0 == h) { c0 = c1; c1 = c2; c2 = c3; c3 = ~0ull; }
        if (lane == 0) cand[(size_t)wave * KCAND + r] = (h < cov) ? h : ~0ull;
    }
}

// ---------------------------------------------------------------------------
// K3: sequential greedy confirm — ONE wave.  Availability bitmask (S bits)
// distributed across lane registers: word w owned by lane (w&63), slot (w>>6).
// 4 rank-slots per substep: lane l = g*16+e holds entry e of rank t+g.
// Avail query = 10 shuffles (no memory in the dep chain).  Later groups
// exclude earlier groups' chosen sites via ballot equality masks (exact:
// removing a non-argmin site never changes an argmin).  Exhausted list ->
// exact full rescan from the register bitmask (rare).  Entries prefetched
// 2 substeps ahead.  Writes assignRank[t] = chosen site index.
// ---------------------------------------------------------------------------
__global__ __launch_bounds__(64, 1)
void k_confirm(const float* __restrict__ locX,
               const float* __restrict__ locY,
               const float* __restrict__ sites,
               const int* __restrict__ order,
               const u64* __restrict__ cand,
               u32* __restrict__ assignRank, int N, int S) {
    const u64 SENT = ~0ull;
    int lane = threadIdx.x;
    const float2* s2 = (const float2*)sites;

    // distributed availability bitmask: m[k] = word (lane + 64k)
    u32 m[10];
    #pragma unroll
    for (int k = 0; k < 10; ++k) {
        int w = lane + 64 * k;
        int base = 32 * w;
        u32 msk;
        if (base + 32 <= S)      msk = 0xFFFFFFFFu;
        else if (base >= S)      msk = 0u;
        else                     msk = (1u << (S - base)) - 1u;
        m[k] = msk;
    }

    int t = 0;
    u64 e_cur = cand[lane];                    // ranks t..t+3
    u64 eA    = cand[64 + lane];               // ranks t+4..t+7
    u64 eB    = cand[128 + lane];              // ranks t+8..t+11

    while (t < N) {
        u64 e = e_cur;
        u32 j = (u32)e;
        int g_of_lane = lane >> 4;
        bool valid = (e != SENT) && (t + g_of_lane < N);

        // availability query via shuffles
        u32 wq = j >> 5;
        int owner = (int)(wq & 63u);
        int slot  = (int)(wq >> 6);
        u32 val = 0;
        #pragma unroll
        for (int k = 0; k < 10; ++k) {
            u32 tk = (u32)__shfl((int)m[k], owner);
            if (slot == k) val = tk;
        }
        bool avail = valid && ((val >> (j & 31u)) & 1u);
        u64 bal = __ballot(avail);

        int ng = (N - t) < 4 ? (N - t) : 4;
        int EX = -1;
        u64 taken_eq = 0;
        for (int g = 0; g < ng; ++g) {
            u64 mg = ((bal >> (16 * g)) & 0xFFFFull) &
                     ~((taken_eq >> (16 * g)) & 0xFFFFull);
            if (mg == 0) { EX = g; break; }
            int pick = __ffsll(mg) - 1;            // smallest key available
            int src  = 16 * g + pick;
            u32 jj   = (u32)__shfl((int)j, src);   // chosen site (uniform)
            taken_eq |= __ballot(j == jj);
            if (lane == 0) assignRank[t + g] = jj;
            // clear availability bit of jj
            u32 cw = jj >> 5;
            int cown = (int)(cw & 63u), cslot = (int)(cw >> 6);
            u32 cbit = 1u << (jj & 31u);
            #pragma unroll
            for (int k = 0; k < 10; ++k)
                if (cslot == k && lane == cown) m[k] &= ~cbit;
        }

        if (EX < 0) {
            t += ng;
            e_cur = eA; eA = eB;
            eB = cand[(size_t)(t + 8) * KCAND + lane];
        } else {
            // exact fallback: full rescan of available sites (rare)
            int inst = order[t + EX];
            float lx = locX[inst], ly = locY[inst];
            u64 best = SENT;
            #pragma unroll
            for (int k = 0; k < 10; ++k) {
                u32 bits = m[k];
                int w = lane + 64 * k;
                while (bits) {
                    int b = __ffs(bits) - 1;
                    bits &= bits - 1;
                    int j2 = 32 * w + b;
                    float2 s = s2[j2];
                    float  d = fabsf(lx - s.x) + fabsf(ly - s.y);
                    u64 kk = ((u64)__float_as_uint(d) << 32) | (u32)j2;
                    best = (kk < best) ? kk : best;
                }
            }
            #pragma unroll
            for (int mm = 32; mm >= 1; mm >>= 1) {
                u64 o = __shfl_xor(best, mm);
                best = (o < best) ? o : best;
            }
            u32 jj = (u32)best;
            if (lane == 0) assignRank[t + EX] = jj;
            u32 cw = jj >> 5;
            int cown = (int)(cw & 63u), cslot = (int)(cw >> 6);
            u32 cbit = 1u << (jj & 31u);
            #pragma unroll
            for (int k = 0; k < 10; ++k)
                if (cslot == k && lane == cown) m[k] &= ~cbit;
            t += EX + 1;
            e_cur = cand[(size_t)t * KCAND + lane];
            eA    = cand[(size_t)(t + 4) * KCAND + lane];
            eB    = cand[(size_t)(t + 8) * KCAND + lane];
        }
    }
}

// ---------------------------------------------------------------------------
// K4: materialize outputs + stats.  Single block.
// ---------------------------------------------------------------------------
__global__ void k_finish(const float* __restrict__ locX,
                         const float* __restrict__ locY,
                         const float* __restrict__ sites,
                         const int* __restrict__ order,
                         const u32* __restrict__ assignRank,
                         float* __restrict__ out, int N) {
    __shared__ float  sMax[256];
    __shared__ double sSum[256];
    int tid = threadIdx.x;
    const float2* s2 = (const float2*)sites;
    float  mx = 0.0f;
    double sm = 0.0;
    for (int t = tid; t < N; t += 256) {
        int i = order[t];
        u32 j = assignRank[t];
        float2 s = s2[j];
        out[i]     = s.x;
        out[N + i] = s.y;
        float mv = fabsf(locX[i] - s.x) + fabsf(locY[i] - s.y);
        mx = fmaxf(mx, mv);
        sm += (double)mv;
    }
    sMax[tid] = mx; sSum[tid] = sm;
    __syncthreads();
    for (int s = 128; s > 0; s >>= 1) {
        if (tid < s) {
            sMax[tid] = fmaxf(sMax[tid], sMax[tid + s]);
            sSum[tid] += sSum[tid + s];
        }
        __syncthreads();
    }
    if (tid == 0) {
        out[2 * N]     = sMax[0];
        out[2 * N + 1] = (float)(sSum[0] / (double)N);
    }
}

extern "C" void kernel_launch(void* const* d_in, const int* in_sizes, int n_in,
                              void* d_out, int out_size, void* d_ws, size_t ws_size,
                              hipStream_t stream) {
    const float* locX      = (const float*)d_in[0];
    const float* locY      = (const float*)d_in[1];
    const float* precondWL = (const float*)d_in[2];
    const float* sites     = (const float*)d_in[3];
    float* out = (float*)d_out;

    int N = in_sizes[0];
    int S = in_sizes[3] / 2;

    char* ws = (char*)d_ws;
    int* order      = (int*)ws;                         // N ints
    u32* assignRank = (u32*)(ws + (size_t)N * 4);       // N u32
    u64* cand       = (u64*)(ws + (size_t)N * 8);       // (N*16 + 192) u64

    int blocks = (N * 64 + 255) / 256;   // one wave per instance / rank slot
    k_rank<<<blocks, 256, 0, stream>>>(precondWL, order, cand, N);
    k_cand<<<blocks, 256, 0, stream>>>(locX, locY, sites, order, cand, N, S);
    k_confirm<<<1, 64, 0, stream>>>(locX, locY, sites, order, cand,
                                    assignRank, N, S);
    k_finish<<<1, 256, 0, stream>>>(locX, locY, sites, order, assignRank,
                                    out, N);
}

// Round 4
// 160.531 us; speedup vs baseline: 55.6301x; 8.6107x over previous
//
#include <hip/hip_runtime.h>
#include <hip/hip_bf16.h>
#include <hip/hip_cooperative_groups.h>

namespace cg = cooperative_groups;

typedef unsigned long long u64;
typedef unsigned int u32;

#define KCAND 16
#define NOPICK 0xFFFFFFFFu
#define SENTV  (~0ull)
#define SOLVE_BLOCKS 16
#define SOLVE_THREADS 256

// ---------------------------------------------------------------------------
// K1: order = stable argsort(-w).  One wave per instance: rank via counting.
// ---------------------------------------------------------------------------
__global__ void k_rank(const float* __restrict__ w, int* __restrict__ order,
                       int N) {
    int gid  = blockIdx.x * blockDim.x + threadIdx.x;
    int wave = gid >> 6, lane = gid & 63;
    if (wave >= N) return;
    float wi = w[wave];
    int cnt = 0;
    for (int j = lane; j < N; j += 64) {
        float wj = w[j];
        cnt += (wj > wi) || (wj == wi && j < wave);
    }
    #pragma unroll
    for (int m = 32; m >= 1; m >>= 1) cnt += __shfl_xor(cnt, m);
    if (lane == 0) order[cnt] = wave;
}

// ---------------------------------------------------------------------------
// K2: per-RANK exact top-16 candidate list (ascending packed key
// (dist_bits<<32)|j), truncated by the coverage bound.  One wave per rank.
// ---------------------------------------------------------------------------
__global__ void k_cand(const float* __restrict__ locX,
                       const float* __restrict__ locY,
                       const float* __restrict__ sites,
                       const int* __restrict__ order,
                       u64* __restrict__ cand, int N, int S) {
    int gid  = blockIdx.x * blockDim.x + threadIdx.x;
    int wave = gid >> 6, lane = gid & 63;   // wave == rank slot t
    if (wave >= N) return;
    int inst = order[wave];
    float lx = locX[inst], ly = locY[inst];
    const float2* s2 = (const float2*)sites;

    u64 c0 = ~0ull, c1 = ~0ull, c2 = ~0ull, c3 = ~0ull;
    for (int j = lane; j < S; j += 64) {
        float2 s = s2[j];
        float  d = fabsf(lx - s.x) + fabsf(ly - s.y);
        u64 k = ((u64)__float_as_uint(d) << 32) | (u32)j;
        if (k < c3) {
            u64 n3 = (k < c2) ? c2 : k;
            u64 n2 = (k < c2) ? ((k < c1) ? c1 : k) : c2;
            u64 n1 = (k < c1) ? ((k < c0) ? c0 : k) : c1;
            u64 n0 = (k < c0) ? k : c0;
            c0 = n0; c1 = n1; c2 = n2; c3 = n3;
        }
    }
    u64 cov = c3;
    #pragma unroll
    for (int m = 32; m >= 1; m >>= 1) {
        u64 o = __shfl_xor(cov, m);
        cov = (o < cov) ? o : cov;
    }
    for (int r = 0; r < KCAND; ++r) {
        u64 h = c0;
        #pragma unroll
        for (int m = 32; m >= 1; m >>= 1) {
            u64 o = __shfl_xor(h, m);
            h = (o < h) ? o : h;
        }
        if (c0 == h) { c0 = c1; c1 = c2; c2 = c3; c3 = ~0ull; }
        if (lane == 0) cand[(size_t)wave * KCAND + r] = (h < cov) ? h : SENTV;
    }
}

// ---------------------------------------------------------------------------
// K3: cooperative Jacobi fixpoint of the greedy recurrence.
//   pick[t] = first candidate of rank t not owned by a rank < t.
//   owner[j] holds (invRoundTag<<12)|rank via atomicMin — newer rounds have
//   strictly smaller tags so stale rounds read as "free" (no clear pass).
//   Exhausted lists fall back to an exact full scan (one wave each).
//   Fixpoint == sequential greedy (induction on smallest differing rank).
//   Requires N <= 4096 and rounds <= 4095 (12-bit packing).
// ---------------------------------------------------------------------------
__global__ __launch_bounds__(SOLVE_THREADS, 1)
void k_solve(const float* __restrict__ locX,
             const float* __restrict__ locY,
             const float* __restrict__ sites,
             const int* __restrict__ order,
             const u64* __restrict__ cand,
             u32* __restrict__ pick, u32* __restrict__ owner,
             u32* __restrict__ queue, u32* __restrict__ ctl,
             float* __restrict__ pMax, double* __restrict__ pSum,
             float* __restrict__ out, int N, int S) {
    cg::grid_group grid = cg::this_grid();
    int gtid = blockIdx.x * blockDim.x + threadIdx.x;
    int gsz  = gridDim.x * blockDim.x;
    int waveId = gtid >> 6, lane = gtid & 63, nWaves = gsz >> 6;
    const float2* s2 = (const float2*)sites;

    // init
    for (int t = gtid; t < N; t += gsz) pick[t] = NOPICK;
    for (int j = gtid; j < S; j += gsz) owner[j] = NOPICK;
    if (gtid < 4) ctl[gtid] = 0;   // ctl[0..1]=qcount parity, ctl[2..3]=changed parity
    grid.sync();

    for (int r = 0; r < 4095; ++r) {
        int par = r & 1;
        u32 prevTag = 4096u - (u32)r;   // tag built by round r-1 (4096 => none)
        u32 curTag  = 4095u - (u32)r;

        // ---- Phase A: list-based pick (one thread per rank) ----
        for (int t = gtid; t < N; t += gsz) {
            const u64* cl = cand + (size_t)t * KCAND;
            u64 e[KCAND];
            #pragma unroll
            for (int q = 0; q < KCAND; ++q) e[q] = cl[q];
            u32 ow[KCAND];
            #pragma unroll
            for (int q = 0; q < KCAND; ++q) {
                u32 ja = (e[q] == SENTV) ? 0u : (u32)e[q];
                ow[q] = owner[ja];
            }
            u32 np = NOPICK;
            bool done = false;
            #pragma unroll
            for (int q = 0; q < KCAND; ++q) {
                bool sent    = (e[q] == SENTV);
                bool blocked = ((ow[q] >> 12) == prevTag) &&
                               ((ow[q] & 0xFFFu) < (u32)t);
                if (!done) {
                    if (sent)          done = true;            // exhausted prefix
                    else if (!blocked) { np = (u32)e[q]; done = true; }
                }
            }
            if (np == NOPICK) {
                u32 qi = atomicAdd(&ctl[par], 1u);
                queue[qi] = (u32)t;
            } else if (np != pick[t]) {
                pick[t] = np;
                atomicOr(&ctl[2 + par], 1u);
            }
        }
        grid.sync();

        // ---- Phase B: exact fallback scans (one wave per exhausted rank) ----
        int nq = (int)ctl[par];
        if (nq > 0) {
            for (int q = waveId; q < nq; q += nWaves) {
                int t = (int)queue[q];
                int inst = order[t];
                float lx = locX[inst], ly = locY[inst];
                u64 best = SENTV;
                for (int j = lane; j < S; j += 64) {
                    u32 v = owner[j];
                    bool blocked = ((v >> 12) == prevTag) &&
                                   ((v & 0xFFFu) < (u32)t);
                    if (!blocked) {
                        float2 s = s2[j];
                        float d = fabsf(lx - s.x) + fabsf(ly - s.y);
                        u64 k = ((u64)__float_as_uint(d) << 32) | (u32)j;
                        best = (k < best) ? k : best;
                    }
                }
                #pragma unroll
                for (int m = 32; m >= 1; m >>= 1) {
                    u64 o = __shfl_xor(best, m);
                    best = (o < best) ? o : best;
                }
                if (lane == 0) {
                    u32 np = (u32)best;
                    if (np != pick[t]) { pick[t] = np; atomicOr(&ctl[2 + par], 1u); }
                }
            }
            grid.sync();
        }

        u32 changed = ctl[2 + par];

        // ---- Phase C: publish claims; reset next round's ctl ----
        for (int t = gtid; t < N; t += gsz)
            atomicMin(&owner[pick[t]], (curTag << 12) | (u32)t);
        if (gtid == 0) { ctl[1 - par] = 0; ctl[2 + (1 - par)] = 0; }
        grid.sync();

        if (!changed) break;
    }

    // ---- outputs + stats ----
    __shared__ float  sMax[SOLVE_THREADS];
    __shared__ double sSum[SOLVE_THREADS];
    float  mx = 0.0f;
    double sm = 0.0;
    for (int t = gtid; t < N; t += gsz) {
        int i = order[t];
        u32 j = pick[t];
        float2 s = s2[j];
        out[i]     = s.x;
        out[N + i] = s.y;
        float mv = fabsf(locX[i] - s.x) + fabsf(locY[i] - s.y);
        mx = fmaxf(mx, mv);
        sm += (double)mv;
    }
    sMax[threadIdx.x] = mx; sSum[threadIdx.x] = sm;
    __syncthreads();
    for (int s = SOLVE_THREADS / 2; s > 0; s >>= 1) {
        if ((int)threadIdx.x < s) {
            sMax[threadIdx.x] = fmaxf(sMax[threadIdx.x], sMax[threadIdx.x + s]);
            sSum[threadIdx.x] += sSum[threadIdx.x + s];
        }
        __syncthreads();
    }
    if (threadIdx.x == 0) { pMax[blockIdx.x] = sMax[0]; pSum[blockIdx.x] = sSum[0]; }
    grid.sync();
    if (gtid == 0) {
        float  M = 0.0f;
        double SS = 0.0;
        for (int b = 0; b < (int)gridDim.x; ++b) {
            M = fmaxf(M, pMax[b]);
            SS += pSum[b];
        }
        out[2 * N]     = M;
        out[2 * N + 1] = (float)(SS / (double)N);
    }
}

extern "C" void kernel_launch(void* const* d_in, const int* in_sizes, int n_in,
                              void* d_out, int out_size, void* d_ws, size_t ws_size,
                              hipStream_t stream) {
    const float* locX      = (const float*)d_in[0];
    const float* locY      = (const float*)d_in[1];
    const float* precondWL = (const float*)d_in[2];
    const float* sites     = (const float*)d_in[3];
    float* out = (float*)d_out;

    int N = in_sizes[0];
    int S = in_sizes[3] / 2;

    char* ws = (char*)d_ws;
    size_t off = 0;
    u64*    cand  = (u64*)(ws + off);    off += (size_t)N * KCAND * 8;
    double* pSum  = (double*)(ws + off); off += SOLVE_BLOCKS * 8;
    int*    order = (int*)(ws + off);    off += (size_t)N * 4;
    u32*    pick  = (u32*)(ws + off);    off += (size_t)N * 4;
    u32*    queue = (u32*)(ws + off);    off += (size_t)N * 4;
    u32*    owner = (u32*)(ws + off);    off += (size_t)S * 4;
    float*  pMax  = (float*)(ws + off);  off += SOLVE_BLOCKS * 4;
    u32*    ctl   = (u32*)(ws + off);    off += 16;

    int blocks = (N * 64 + 255) / 256;   // one wave per instance / rank slot
    k_rank<<<blocks, 256, 0, stream>>>(precondWL, order, N);
    k_cand<<<blocks, 256, 0, stream>>>(locX, locY, sites, order, cand, N, S);

    void* args[] = {
        (void*)&locX, (void*)&locY, (void*)&sites, (void*)&order,
        (void*)&cand, (void*)&pick, (void*)&owner, (void*)&queue,
        (void*)&ctl,  (void*)&pMax, (void*)&pSum,  (void*)&out,
        (void*)&N,    (void*)&S
    };
    hipLaunchCooperativeKernel((void*)k_solve, dim3(SOLVE_BLOCKS),
                               dim3(SOLVE_THREADS), args, 0, stream);
}

// Round 5
// 135.573 us; speedup vs baseline: 65.8714x; 1.1841x over previous
//
#include <hip/hip_runtime.h>
#include <hip/hip_bf16.h>
#include <hip/hip_cooperative_groups.h>

namespace cg = cooperative_groups;

typedef unsigned long long u64;
typedef unsigned int u32;

#define KCAND 16
#define NOPICK 0xFFFFFFFFu
#define SENTV  (~0ull)
#define SOLVE_BLOCKS 16
#define SOLVE_THREADS 256
#define NB 512
#define YMAX_CONST 480.0f
#define R0_INIT 10.0f

__device__ __forceinline__ int ybin(float y) {
    int b = (int)(y * ((float)NB / YMAX_CONST));
    return b < 0 ? 0 : (b > NB - 1 ? NB - 1 : b);
}

// ---------------------------------------------------------------------------
// K0: y-binning structure (single block): LDS histogram -> LDS scan ->
// scatter sites into y-sorted packed array spack[p] = (x, y, bits(j), 0).
// ---------------------------------------------------------------------------
__global__ __launch_bounds__(1024)
void k_build(const float* __restrict__ sites, float4* __restrict__ spack,
             u32* __restrict__ binStart, int S) {
    __shared__ u32 sa[NB], sb[NB], curs[NB];
    int tid = threadIdx.x;
    for (int i = tid; i < NB; i += 1024) sa[i] = 0;
    __syncthreads();
    const float2* s2 = (const float2*)sites;
    for (int j = tid; j < S; j += 1024)
        atomicAdd(&sa[ybin(s2[j].y)], 1u);
    __syncthreads();
    u32* src = sa; u32* dst = sb;
    for (int d = 1; d < NB; d <<= 1) {         // inclusive scan, ping-pong
        for (int i = tid; i < NB; i += 1024)
            dst[i] = src[i] + (i >= d ? src[i - d] : 0u);
        __syncthreads();
        u32* t = src; src = dst; dst = t;
    }
    for (int i = tid; i < NB; i += 1024) {
        u32 e = (i == 0) ? 0u : src[i - 1];    // exclusive
        binStart[i] = e;
        curs[i] = e;
    }
    if (tid == 0) binStart[NB] = (u32)S;
    __syncthreads();
    for (int j = tid; j < S; j += 1024) {
        float2 s = s2[j];
        u32 pos = atomicAdd(&curs[ybin(s.y)], 1u);
        spack[pos] = make_float4(s.x, s.y, __uint_as_float((u32)j), 0.0f);
    }
}

// ---------------------------------------------------------------------------
// K1: order = stable argsort(-w).  One wave per instance.
// ---------------------------------------------------------------------------
__global__ void k_rank(const float* __restrict__ w, int* __restrict__ order,
                       int N) {
    int gid  = blockIdx.x * blockDim.x + threadIdx.x;
    int wave = gid >> 6, lane = gid & 63;
    if (wave >= N) return;
    float wi = w[wave];
    int cnt = 0;
    for (int j = lane; j < N; j += 64) {
        float wj = w[j];
        cnt += (wj > wi) || (wj == wi && j < wave);
    }
    #pragma unroll
    for (int m = 32; m >= 1; m >>= 1) cnt += __shfl_xor(cnt, m);
    if (lane == 0) order[cnt] = wave;
}

// ---------------------------------------------------------------------------
// K2: per-rank exact top-16 via windowed search.  One wave per rank.
// Window = y-bins overlapping [ly-R, ly+R].  Termination: >=16 in-window
// sites with d <= R-1e-3  =>  every excluded site (|dy| > R - fp noise) has
// strictly larger key, so true top-16 is inside the window.  Else R *= 2.
// Per-lane sorted top-8 + dropped-min coverage -> exact sorted prefix;
// rare filtered re-extraction guarantees a full exact 16-list.
// ---------------------------------------------------------------------------
__global__ __launch_bounds__(256)
void k_cand(const float* __restrict__ locX, const float* __restrict__ locY,
            const int* __restrict__ order,
            const float4* __restrict__ spack,
            const u32* __restrict__ binStart,
            u64* __restrict__ cand, int N, int S) {
    int gid  = blockIdx.x * blockDim.x + threadIdx.x;
    int wave = gid >> 6, lane = gid & 63;   // wave == rank slot
    if (wave >= N) return;
    int inst = order[wave];
    float lx = locX[inst], ly = locY[inst];

    u64 c[8];
    u64 dropped = SENTV;
    float R = R0_INIT;
    int start = 0, end = 0;

    for (int attempt = 0; attempt < 8; ++attempt) {
        #pragma unroll
        for (int q = 0; q < 8; ++q) c[q] = SENTV;
        dropped = SENTV;
        int b0 = ybin(ly - R), b1 = ybin(ly + R);
        start = (int)binStart[b0];
        end   = (int)binStart[b1 + 1];
        float Rm = R - 1e-3f;
        int cnt = 0;
        for (int p = start + lane; p < end; p += 64) {
            float4 s = spack[p];
            float d = fabsf(lx - s.x) + fabsf(ly - s.y);
            u64 k = ((u64)__float_as_uint(d) << 32) |
                    (u64)(u32)__float_as_uint(s.z);
            cnt += (d <= Rm) ? 1 : 0;
            if (k < c[7]) {
                if (c[7] != SENTV) dropped = (c[7] < dropped) ? c[7] : dropped;
                u64 x = k;
                #pragma unroll
                for (int q = 0; q < 8; ++q) {
                    u64 mn = (x < c[q]) ? x : c[q];
                    u64 mx = (x < c[q]) ? c[q] : x;
                    c[q] = mn; x = mx;
                }
            } else {
                dropped = (k < dropped) ? k : dropped;
            }
        }
        #pragma unroll
        for (int m = 32; m >= 1; m >>= 1) cnt += __shfl_xor(cnt, m);
        if (cnt >= KCAND || (end - start) >= S) break;
        R *= 2.0f;
    }

    u64 cov = dropped;   // all keys < cov are retained in some lane's list
    #pragma unroll
    for (int m = 32; m >= 1; m >>= 1) {
        u64 o = __shfl_xor(cov, m);
        cov = (o < cov) ? o : cov;
    }

    int valid = 0;
    for (int r = 0; r < KCAND; ++r) {
        u64 h = c[0];
        #pragma unroll
        for (int m = 32; m >= 1; m >>= 1) {
            u64 o = __shfl_xor(h, m);
            h = (o < h) ? o : h;
        }
        if (c[0] == h && h != SENTV) {   // unique winner (keys unique)
            #pragma unroll
            for (int q = 0; q < 7; ++q) c[q] = c[q + 1];
            c[7] = SENTV;
        }
        u64 outv = (h < cov) ? h : SENTV;
        valid += (outv != SENTV) ? 1 : 0;
        if (lane == 0) cand[(size_t)wave * KCAND + r] = outv;
    }

    // rare exact slow path: coverage truncated the list below what the
    // window can supply -> filtered re-extraction (exact top-need).
    int nWin = end - start;
    int need = nWin < KCAND ? nWin : KCAND;
    if (valid < need) {
        u64 last = 0;
        for (int r = 0; r < KCAND; ++r) {
            u64 best = SENTV;
            if (r < need) {
                for (int p = start + lane; p < end; p += 64) {
                    float4 s = spack[p];
                    float d = fabsf(lx - s.x) + fabsf(ly - s.y);
                    u64 k = ((u64)__float_as_uint(d) << 32) |
                            (u64)(u32)__float_as_uint(s.z);
                    if (r == 0 || k > last) best = (k < best) ? k : best;
                }
                #pragma unroll
                for (int m = 32; m >= 1; m >>= 1) {
                    u64 o = __shfl_xor(best, m);
                    best = (o < best) ? o : best;
                }
                last = best;
            }
            if (lane == 0) cand[(size_t)wave * KCAND + r] = best;
        }
    }
}

// ---------------------------------------------------------------------------
// K3: cooperative Jacobi fixpoint of the greedy recurrence (unchanged).
// ---------------------------------------------------------------------------
__global__ __launch_bounds__(SOLVE_THREADS, 1)
void k_solve(const float* __restrict__ locX,
             const float* __restrict__ locY,
             const float* __restrict__ sites,
             const int* __restrict__ order,
             const u64* __restrict__ cand,
             u32* __restrict__ pick, u32* __restrict__ owner,
             u32* __restrict__ queue, u32* __restrict__ ctl,
             float* __restrict__ pMax, double* __restrict__ pSum,
             float* __restrict__ out, int N, int S) {
    cg::grid_group grid = cg::this_grid();
    int gtid = blockIdx.x * blockDim.x + threadIdx.x;
    int gsz  = gridDim.x * blockDim.x;
    int waveId = gtid >> 6, lane = gtid & 63, nWaves = gsz >> 6;
    const float2* s2 = (const float2*)sites;

    for (int t = gtid; t < N; t += gsz) pick[t] = NOPICK;
    for (int j = gtid; j < S; j += gsz) owner[j] = NOPICK;
    if (gtid < 4) ctl[gtid] = 0;
    grid.sync();

    for (int r = 0; r < 4095; ++r) {
        int par = r & 1;
        u32 prevTag = 4096u - (u32)r;
        u32 curTag  = 4095u - (u32)r;

        for (int t = gtid; t < N; t += gsz) {
            const u64* cl = cand + (size_t)t * KCAND;
            u64 e[KCAND];
            #pragma unroll
            for (int q = 0; q < KCAND; ++q) e[q] = cl[q];
            u32 ow[KCAND];
            #pragma unroll
            for (int q = 0; q < KCAND; ++q) {
                u32 ja = (e[q] == SENTV) ? 0u : (u32)e[q];
                ow[q] = owner[ja];
            }
            u32 np = NOPICK;
            bool done = false;
            #pragma unroll
            for (int q = 0; q < KCAND; ++q) {
                bool sent    = (e[q] == SENTV);
                bool blocked = ((ow[q] >> 12) == prevTag) &&
                               ((ow[q] & 0xFFFu) < (u32)t);
                if (!done) {
                    if (sent)          done = true;
                    else if (!blocked) { np = (u32)e[q]; done = true; }
                }
            }
            if (np == NOPICK) {
                u32 qi = atomicAdd(&ctl[par], 1u);
                queue[qi] = (u32)t;
            } else if (np != pick[t]) {
                pick[t] = np;
                atomicOr(&ctl[2 + par], 1u);
            }
        }
        grid.sync();

        int nq = (int)ctl[par];
        if (nq > 0) {
            for (int q = waveId; q < nq; q += nWaves) {
                int t = (int)queue[q];
                int inst = order[t];
                float lx = locX[inst], ly = locY[inst];
                u64 best = SENTV;
                for (int j = lane; j < S; j += 64) {
                    u32 v = owner[j];
                    bool blocked = ((v >> 12) == prevTag) &&
                                   ((v & 0xFFFu) < (u32)t);
                    if (!blocked) {
                        float2 s = s2[j];
                        float d = fabsf(lx - s.x) + fabsf(ly - s.y);
                        u64 k = ((u64)__float_as_uint(d) << 32) | (u32)j;
                        best = (k < best) ? k : best;
                    }
                }
                #pragma unroll
                for (int m = 32; m >= 1; m >>= 1) {
                    u64 o = __shfl_xor(best, m);
                    best = (o < best) ? o : best;
                }
                if (lane == 0) {
                    u32 np = (u32)best;
                    if (np != pick[t]) { pick[t] = np; atomicOr(&ctl[2 + par], 1u); }
                }
            }
            grid.sync();
        }

        u32 changed = ctl[2 + par];

        for (int t = gtid; t < N; t += gsz)
            atomicMin(&owner[pick[t]], (curTag << 12) | (u32)t);
        if (gtid == 0) { ctl[1 - par] = 0; ctl[2 + (1 - par)] = 0; }
        grid.sync();

        if (!changed) break;
    }

    __shared__ float  sMax[SOLVE_THREADS];
    __shared__ double sSum[SOLVE_THREADS];
    float  mx = 0.0f;
    double sm = 0.0;
    for (int t = gtid; t < N; t += gsz) {
        int i = order[t];
        u32 j = pick[t];
        float2 s = s2[j];
        out[i]     = s.x;
        out[N + i] = s.y;
        float mv = fabsf(locX[i] - s.x) + fabsf(locY[i] - s.y);
        mx = fmaxf(mx, mv);
        sm += (double)mv;
    }
    sMax[threadIdx.x] = mx; sSum[threadIdx.x] = sm;
    __syncthreads();
    for (int s = SOLVE_THREADS / 2; s > 0; s >>= 1) {
        if ((int)threadIdx.x < s) {
            sMax[threadIdx.x] = fmaxf(sMax[threadIdx.x], sMax[threadIdx.x + s]);
            sSum[threadIdx.x] += sSum[threadIdx.x + s];
        }
        __syncthreads();
    }
    if (threadIdx.x == 0) { pMax[blockIdx.x] = sMax[0]; pSum[blockIdx.x] = sSum[0]; }
    grid.sync();
    if (gtid == 0) {
        float  M = 0.0f;
        double SS = 0.0;
        for (int b = 0; b < (int)gridDim.x; ++b) {
            M = fmaxf(M, pMax[b]);
            SS += pSum[b];
        }
        out[2 * N]     = M;
        out[2 * N + 1] = (float)(SS / (double)N);
    }
}

extern "C" void kernel_launch(void* const* d_in, const int* in_sizes, int n_in,
                              void* d_out, int out_size, void* d_ws, size_t ws_size,
                              hipStream_t stream) {
    const float* locX      = (const float*)d_in[0];
    const float* locY      = (const float*)d_in[1];
    const float* precondWL = (const float*)d_in[2];
    const float* sites     = (const float*)d_in[3];
    float* out = (float*)d_out;

    int N = in_sizes[0];
    int S = in_sizes[3] / 2;

    char* ws = (char*)d_ws;
    size_t off = 0;
    u64*    cand     = (u64*)(ws + off);    off += (size_t)N * KCAND * 8;  // 512K
    float4* spack    = (float4*)(ws + off); off += (size_t)S * 16;         // 320K
    double* pSum     = (double*)(ws + off); off += SOLVE_BLOCKS * 8;
    int*    order    = (int*)(ws + off);    off += (size_t)N * 4;
    u32*    pick     = (u32*)(ws + off);    off += (size_t)N * 4;
    u32*    queue    = (u32*)(ws + off);    off += (size_t)N * 4;
    u32*    owner    = (u32*)(ws + off);    off += (size_t)S * 4;
    u32*    binStart = (u32*)(ws + off);    off += (NB + 1) * 4;
    float*  pMax     = (float*)(ws + off);  off += SOLVE_BLOCKS * 4;
    u32*    ctl      = (u32*)(ws + off);    off += 16;

    int blocks = (N * 64 + 255) / 256;
    k_rank<<<blocks, 256, 0, stream>>>(precondWL, order, N);
    k_build<<<1, 1024, 0, stream>>>(sites, spack, binStart, S);
    k_cand<<<blocks, 256, 0, stream>>>(locX, locY, order, spack, binStart,
                                       cand, N, S);

    void* args[] = {
        (void*)&locX, (void*)&locY, (void*)&sites, (void*)&order,
        (void*)&cand, (void*)&pick, (void*)&owner, (void*)&queue,
        (void*)&ctl,  (void*)&pMax, (void*)&pSum,  (void*)&out,
        (void*)&N,    (void*)&S
    };
    hipLaunchCooperativeKernel((void*)k_solve, dim3(SOLVE_BLOCKS),
                               dim3(SOLVE_THREADS), args, 0, stream);
}

// Round 6
// 91.872 us; speedup vs baseline: 97.2045x; 1.4757x over previous
//
#include <hip/hip_runtime.h>
#include <hip/hip_bf16.h>
#include <hip/hip_cooperative_groups.h>

namespace cg = cooperative_groups;

typedef unsigned long long u64;
typedef unsigned int u32;

#define KCAND 16
#define NOPICK 0xFFFFFFFFu
#define SENTV  (~0ull)
#define SOLVE_BLOCKS 16
#define SOLVE_THREADS 256
#define NB 512
#define YMAX_CONST 480.0f
#define R0_INIT 10.0f

__device__ __forceinline__ int ybin(float y) {
    int b = (int)(y * ((float)NB / YMAX_CONST));
    return b < 0 ? 0 : (b > NB - 1 ? NB - 1 : b);
}

// ---------------------------------------------------------------------------
// K0: y-binning structure (single block): LDS histogram -> LDS scan ->
// scatter sites into y-sorted packed array spack[p] = (x, y, bits(j), 0).
// ---------------------------------------------------------------------------
__global__ __launch_bounds__(1024)
void k_build(const float* __restrict__ sites, float4* __restrict__ spack,
             u32* __restrict__ binStart, int S) {
    __shared__ u32 sa[NB], sb[NB], curs[NB];
    int tid = threadIdx.x;
    for (int i = tid; i < NB; i += 1024) sa[i] = 0;
    __syncthreads();
    const float2* s2 = (const float2*)sites;
    for (int j = tid; j < S; j += 1024)
        atomicAdd(&sa[ybin(s2[j].y)], 1u);
    __syncthreads();
    u32* src = sa; u32* dst = sb;
    for (int d = 1; d < NB; d <<= 1) {
        for (int i = tid; i < NB; i += 1024)
            dst[i] = src[i] + (i >= d ? src[i - d] : 0u);
        __syncthreads();
        u32* t = src; src = dst; dst = t;
    }
    for (int i = tid; i < NB; i += 1024) {
        u32 e = (i == 0) ? 0u : src[i - 1];
        binStart[i] = e;
        curs[i] = e;
    }
    if (tid == 0) binStart[NB] = (u32)S;
    __syncthreads();
    for (int j = tid; j < S; j += 1024) {
        float2 s = s2[j];
        u32 pos = atomicAdd(&curs[ybin(s.y)], 1u);
        spack[pos] = make_float4(s.x, s.y, __uint_as_float((u32)j), 0.0f);
    }
}

// ---------------------------------------------------------------------------
// K1: order = stable argsort(-w).  One wave per instance.
// ---------------------------------------------------------------------------
__global__ void k_rank(const float* __restrict__ w, int* __restrict__ order,
                       int N) {
    int gid  = blockIdx.x * blockDim.x + threadIdx.x;
    int wave = gid >> 6, lane = gid & 63;
    if (wave >= N) return;
    float wi = w[wave];
    int cnt = 0;
    for (int j = lane; j < N; j += 64) {
        float wj = w[j];
        cnt += (wj > wi) || (wj == wi && j < wave);
    }
    #pragma unroll
    for (int m = 32; m >= 1; m >>= 1) cnt += __shfl_xor(cnt, m);
    if (lane == 0) order[cnt] = wave;
}

// ---------------------------------------------------------------------------
// K2: per-rank exact top-16 via windowed search (unchanged from round 5).
// ---------------------------------------------------------------------------
__global__ __launch_bounds__(256)
void k_cand(const float* __restrict__ locX, const float* __restrict__ locY,
            const int* __restrict__ order,
            const float4* __restrict__ spack,
            const u32* __restrict__ binStart,
            u64* __restrict__ cand, int N, int S) {
    int gid  = blockIdx.x * blockDim.x + threadIdx.x;
    int wave = gid >> 6, lane = gid & 63;
    if (wave >= N) return;
    int inst = order[wave];
    float lx = locX[inst], ly = locY[inst];

    u64 c[8];
    u64 dropped = SENTV;
    float R = R0_INIT;
    int start = 0, end = 0;

    for (int attempt = 0; attempt < 8; ++attempt) {
        #pragma unroll
        for (int q = 0; q < 8; ++q) c[q] = SENTV;
        dropped = SENTV;
        int b0 = ybin(ly - R), b1 = ybin(ly + R);
        start = (int)binStart[b0];
        end   = (int)binStart[b1 + 1];
        float Rm = R - 1e-3f;
        int cnt = 0;
        for (int p = start + lane; p < end; p += 64) {
            float4 s = spack[p];
            float d = fabsf(lx - s.x) + fabsf(ly - s.y);
            u64 k = ((u64)__float_as_uint(d) << 32) |
                    (u64)(u32)__float_as_uint(s.z);
            cnt += (d <= Rm) ? 1 : 0;
            if (k < c[7]) {
                if (c[7] != SENTV) dropped = (c[7] < dropped) ? c[7] : dropped;
                u64 x = k;
                #pragma unroll
                for (int q = 0; q < 8; ++q) {
                    u64 mn = (x < c[q]) ? x : c[q];
                    u64 mx = (x < c[q]) ? c[q] : x;
                    c[q] = mn; x = mx;
                }
            } else {
                dropped = (k < dropped) ? k : dropped;
            }
        }
        #pragma unroll
        for (int m = 32; m >= 1; m >>= 1) cnt += __shfl_xor(cnt, m);
        if (cnt >= KCAND || (end - start) >= S) break;
        R *= 2.0f;
    }

    u64 cov = dropped;
    #pragma unroll
    for (int m = 32; m >= 1; m >>= 1) {
        u64 o = __shfl_xor(cov, m);
        cov = (o < cov) ? o : cov;
    }

    int valid = 0;
    for (int r = 0; r < KCAND; ++r) {
        u64 h = c[0];
        #pragma unroll
        for (int m = 32; m >= 1; m >>= 1) {
            u64 o = __shfl_xor(h, m);
            h = (o < h) ? o : h;
        }
        if (c[0] == h && h != SENTV) {
            #pragma unroll
            for (int q = 0; q < 7; ++q) c[q] = c[q + 1];
            c[7] = SENTV;
        }
        u64 outv = (h < cov) ? h : SENTV;
        valid += (outv != SENTV) ? 1 : 0;
        if (lane == 0) cand[(size_t)wave * KCAND + r] = outv;
    }

    int nWin = end - start;
    int need = nWin < KCAND ? nWin : KCAND;
    if (valid < need) {
        u64 last = 0;
        for (int r = 0; r < KCAND; ++r) {
            u64 best = SENTV;
            if (r < need) {
                for (int p = start + lane; p < end; p += 64) {
                    float4 s = spack[p];
                    float d = fabsf(lx - s.x) + fabsf(ly - s.y);
                    u64 k = ((u64)__float_as_uint(d) << 32) |
                            (u64)(u32)__float_as_uint(s.z);
                    if (r == 0 || k > last) best = (k < best) ? k : best;
                }
                #pragma unroll
                for (int m = 32; m >= 1; m >>= 1) {
                    u64 o = __shfl_xor(best, m);
                    best = (o < best) ? o : best;
                }
                last = best;
            }
            if (lane == 0) cand[(size_t)wave * KCAND + r] = best;
        }
    }
}

// ---------------------------------------------------------------------------
// K3: Suitor-style asynchronous greedy fixpoint.
// owner[j] = (rank<<5)|(pos+1) via atomicMin (device scope).  A thread walks
// its rank's candidate list; on winning a claim that displaced a parked rank
// it INHERITS that rank (resume pos from the packed value).  Owners only
// decrease, so "lost to lower rank" is permanent -> stable state == exact
// sequential greedy.  Exhausted lists (rare) go to a queued exact-scan
// fallback loop with claim-retry.  ~4 grid syncs total, no rounds.
// ---------------------------------------------------------------------------
__global__ __launch_bounds__(SOLVE_THREADS, 1)
void k_solve(const float* __restrict__ locX,
             const float* __restrict__ locY,
             const float* __restrict__ sites,
             const int* __restrict__ order,
             const u64* __restrict__ cand,
             u32* __restrict__ pick, u32* __restrict__ owner,
             u32* __restrict__ q0, u32* __restrict__ q1,
             u32* __restrict__ ctl,
             float* __restrict__ pMax, double* __restrict__ pSum,
             float* __restrict__ out, int N, int S) {
    cg::grid_group grid = cg::this_grid();
    int gtid = blockIdx.x * blockDim.x + threadIdx.x;
    int gsz  = gridDim.x * blockDim.x;
    int waveId = gtid >> 6, lane = gtid & 63, nWaves = gsz >> 6;
    const float2* s2 = (const float2*)sites;

    for (int j = gtid; j < S; j += gsz) owner[j] = NOPICK;
    for (int t = gtid; t < N; t += gsz) pick[t] = 0;
    if (gtid < 2) ctl[gtid] = 0;
    grid.sync();

    // ---- Phase 1: asynchronous displacement chains ----
    for (int t0 = gtid; t0 < N; t0 += gsz) {
        int t = t0, p = 0;
        for (int step = 0; step < (1 << 20); ++step) {
            if (p >= KCAND) { u32 qi = atomicAdd(&ctl[0], 1u); q0[qi] = (u32)t; break; }
            u64 e = cand[(size_t)t * KCAND + p];
            if (e == SENTV) { u32 qi = atomicAdd(&ctl[0], 1u); q0[qi] = (u32)t; break; }
            u32 j = (u32)e;
            u32 packed = ((u32)t << 5) | (u32)(p + 1);
            u32 old = atomicMin(&owner[j], packed);
            if (old <= packed) { ++p; continue; }       // lost to lower rank
            if (old != NOPICK) {                        // displaced parked rank
                t = (int)(old >> 5); p = (int)(old & 31u); continue;
            }
            break;                                      // claimed free site
        }
    }
    grid.sync();

    // ---- Fallback loop (rare): exact scan for exhausted lists ----
    u32* qa = q0; u32* qb = q1; int cin = 0;
    for (int iter = 0; iter < 64; ++iter) {
        int nq = (int)ctl[cin];
        if (nq == 0) break;
        for (int q = waveId; q < nq; q += nWaves) {
            int t = (int)qa[q];
            int inst = order[t];
            float lx = locX[inst], ly = locY[inst];
            u64 best = SENTV;
            for (int j = lane; j < S; j += 64) {
                u32 v = owner[j];
                if ((v >> 5) > (u32)t) {       // not taken by lower rank
                    float2 s = s2[j];
                    float d = fabsf(lx - s.x) + fabsf(ly - s.y);
                    u64 k = ((u64)__float_as_uint(d) << 32) | (u32)j;
                    best = (k < best) ? k : best;
                }
            }
            #pragma unroll
            for (int m = 32; m >= 1; m >>= 1) {
                u64 o = __shfl_xor(best, m);
                best = (o < best) ? o : best;
            }
            if (lane == 0) {
                u32 jj = (u32)best;
                u32 packed = ((u32)t << 5) | 31u;
                u32 old = atomicMin(&owner[jj], packed);
                if (old <= packed) {
                    u32 qi = atomicAdd(&ctl[1 - cin], 1u); qb[qi] = (u32)t;
                } else if (old != NOPICK) {
                    int t2 = (int)(old >> 5), p2 = (int)(old & 31u);
                    for (int step = 0; step < (1 << 20); ++step) {
                        if (p2 >= KCAND) { u32 qi = atomicAdd(&ctl[1 - cin], 1u); qb[qi] = (u32)t2; break; }
                        u64 e = cand[(size_t)t2 * KCAND + p2];
                        if (e == SENTV) { u32 qi = atomicAdd(&ctl[1 - cin], 1u); qb[qi] = (u32)t2; break; }
                        u32 j2 = (u32)e;
                        u32 pk2 = ((u32)t2 << 5) | (u32)(p2 + 1);
                        u32 o2 = atomicMin(&owner[j2], pk2);
                        if (o2 <= pk2) { ++p2; continue; }
                        if (o2 != NOPICK) { t2 = (int)(o2 >> 5); p2 = (int)(o2 & 31u); continue; }
                        break;
                    }
                }
            }
        }
        grid.sync();
        if (gtid == 0) ctl[cin] = 0;
        u32* tq = qa; qa = qb; qb = tq;
        cin = 1 - cin;
        grid.sync();
    }

    // ---- Recover per-rank assignment from owner[] ----
    for (int j = gtid; j < S; j += gsz) {
        u32 v = owner[j];
        if (v != NOPICK) pick[v >> 5] = (u32)j;
    }
    grid.sync();

    // ---- Outputs + stats ----
    __shared__ float  sMax[SOLVE_THREADS];
    __shared__ double sSum[SOLVE_THREADS];
    float  mx = 0.0f;
    double sm = 0.0;
    for (int t = gtid; t < N; t += gsz) {
        int i = order[t];
        u32 j = pick[t];
        float2 s = s2[j];
        out[i]     = s.x;
        out[N + i] = s.y;
        float mv = fabsf(locX[i] - s.x) + fabsf(locY[i] - s.y);
        mx = fmaxf(mx, mv);
        sm += (double)mv;
    }
    sMax[threadIdx.x] = mx; sSum[threadIdx.x] = sm;
    __syncthreads();
    for (int s = SOLVE_THREADS / 2; s > 0; s >>= 1) {
        if ((int)threadIdx.x < s) {
            sMax[threadIdx.x] = fmaxf(sMax[threadIdx.x], sMax[threadIdx.x + s]);
            sSum[threadIdx.x] += sSum[threadIdx.x + s];
        }
        __syncthreads();
    }
    if (threadIdx.x == 0) { pMax[blockIdx.x] = sMax[0]; pSum[blockIdx.x] = sSum[0]; }
    grid.sync();
    if (gtid == 0) {
        float  M = 0.0f;
        double SS = 0.0;
        for (int b = 0; b < (int)gridDim.x; ++b) {
            M = fmaxf(M, pMax[b]);
            SS += pSum[b];
        }
        out[2 * N]     = M;
        out[2 * N + 1] = (float)(SS / (double)N);
    }
}

extern "C" void kernel_launch(void* const* d_in, const int* in_sizes, int n_in,
                              void* d_out, int out_size, void* d_ws, size_t ws_size,
                              hipStream_t stream) {
    const float* locX      = (const float*)d_in[0];
    const float* locY      = (const float*)d_in[1];
    const float* precondWL = (const float*)d_in[2];
    const float* sites     = (const float*)d_in[3];
    float* out = (float*)d_out;

    int N = in_sizes[0];
    int S = in_sizes[3] / 2;

    char* ws = (char*)d_ws;
    size_t off = 0;
    u64*    cand     = (u64*)(ws + off);    off += (size_t)N * KCAND * 8;
    float4* spack    = (float4*)(ws + off); off += (size_t)S * 16;
    double* pSum     = (double*)(ws + off); off += SOLVE_BLOCKS * 8;
    int*    order    = (int*)(ws + off);    off += (size_t)N * 4;
    u32*    pick     = (u32*)(ws + off);    off += (size_t)N * 4;
    u32*    q0       = (u32*)(ws + off);    off += (size_t)N * 4;
    u32*    q1       = (u32*)(ws + off);    off += (size_t)N * 4;
    u32*    owner    = (u32*)(ws + off);    off += (size_t)S * 4;
    u32*    binStart = (u32*)(ws + off);    off += (NB + 1) * 4;
    float*  pMax     = (float*)(ws + off);  off += SOLVE_BLOCKS * 4;
    u32*    ctl      = (u32*)(ws + off);    off += 16;

    int blocks = (N * 64 + 255) / 256;
    k_rank<<<blocks, 256, 0, stream>>>(precondWL, order, N);
    k_build<<<1, 1024, 0, stream>>>(sites, spack, binStart, S);
    k_cand<<<blocks, 256, 0, stream>>>(locX, locY, order, spack, binStart,
                                       cand, N, S);

    void* args[] = {
        (void*)&locX, (void*)&locY, (void*)&sites, (void*)&order,
        (void*)&cand, (void*)&pick, (void*)&owner, (void*)&q0, (void*)&q1,
        (void*)&ctl,  (void*)&pMax, (void*)&pSum,  (void*)&out,
        (void*)&N,    (void*)&S
    };
    hipLaunchCooperativeKernel((void*)k_solve, dim3(SOLVE_BLOCKS),
                               dim3(SOLVE_THREADS), args, 0, stream);
}